// Round 7
// baseline (357.102 us; speedup 1.0000x reference)
//
#include <hip/hip_runtime.h>
#include <hip/hip_bf16.h>

typedef __bf16 bf16_t;
typedef bf16_t bf16x8 __attribute__((ext_vector_type(8)));
typedef bf16_t bf16x4 __attribute__((ext_vector_type(4)));
typedef float f32x4 __attribute__((ext_vector_type(4)));
typedef _Float16 f16x2 __attribute__((ext_vector_type(2)));

#define MFMA16(a, b, c) __builtin_amdgcn_mfma_f32_16x16x32_bf16(a, b, c, 0, 0, 0)

typedef __attribute__((address_space(3))) unsigned int lds_u32_t;
typedef __attribute__((address_space(1))) const unsigned int glb_u32_t;

__device__ __forceinline__ void gload16(const void* g, void* l) {
    __builtin_amdgcn_global_load_lds((glb_u32_t*)g, (lds_u32_t*)l, 16, 0, 0);
}

// swizzled LDS read: row stride 128B, byte-col ^= (row&7)<<4
__device__ __forceinline__ bf16x8 lds8(const bf16_t* base, int row, int cb) {
    return *reinterpret_cast<const bf16x8*>(
        reinterpret_cast<const char*>(base) + row * 128 + (cb ^ ((row & 7) << 4)));
}

// ---------------------------------------------------------------------------
// Pre-pass 1: X fp32 -> bf16
// ---------------------------------------------------------------------------
__global__ __launch_bounds__(256) void convert_x(
    const float* __restrict__ X, bf16_t* __restrict__ Xb)
{
    const size_t i = ((size_t)blockIdx.x * 256 + threadIdx.x) * 8;
    const float4 v0 = *reinterpret_cast<const float4*>(&X[i]);
    const float4 v1 = *reinterpret_cast<const float4*>(&X[i + 4]);
    bf16x8 o;
    o[0] = (bf16_t)v0.x; o[1] = (bf16_t)v0.y; o[2] = (bf16_t)v0.z; o[3] = (bf16_t)v0.w;
    o[4] = (bf16_t)v1.x; o[5] = (bf16_t)v1.y; o[6] = (bf16_t)v1.z; o[7] = (bf16_t)v1.w;
    *reinterpret_cast<bf16x8*>(&Xb[i]) = o;
}

// ---------------------------------------------------------------------------
// Pre-pass 2: W [k][n] fp32 -> Wt [mat][n][k] bf16; K-matrix scaled log2(e)/8.
// ---------------------------------------------------------------------------
__global__ __launch_bounds__(256) void transpose_w(
    const float* __restrict__ Wq, const float* __restrict__ Wk,
    const float* __restrict__ Wv, bf16_t* __restrict__ Wt)
{
    __shared__ float T[64][65];
    const int mat = blockIdx.z;
    const float* W = (mat == 0) ? Wq : (mat == 1 ? Wk : Wv);
    const int k0 = blockIdx.x * 64, n0 = blockIdx.y * 64;
    const int r = threadIdx.x >> 4, c4 = (threadIdx.x & 15) * 4;

    for (int rep = 0; rep < 4; ++rep) {
        const int row = r + rep * 16;
        const float4 v = *reinterpret_cast<const float4*>(&W[(size_t)(k0 + row) * 512 + n0 + c4]);
        T[row][c4 + 0] = v.x; T[row][c4 + 1] = v.y;
        T[row][c4 + 2] = v.z; T[row][c4 + 3] = v.w;
    }
    __syncthreads();
    const float scl = (mat == 1) ? 0.1803368801111204f : 1.0f;  // log2(e)/8
    for (int rep = 0; rep < 4; ++rep) {
        const int nrow = r + rep * 16;
        bf16x4 o;
        for (int e = 0; e < 4; ++e) o[e] = (bf16_t)(T[c4 + e][nrow] * scl);
        *reinterpret_cast<bf16x4*>(&Wt[(size_t)mat * 262144 + (size_t)(n0 + nrow) * 512 + k0 + c4]) = o;
    }
}

// ---------------------------------------------------------------------------
// bf16 projection GEMM, 128x128 tile, BK=64, 4 waves (each 64x64 out).
// grid (64, 12): mat = y>>2, n0 = (y&3)*128.
// mat 0 -> Qb row-major; 1 -> Kb row-major (K pre-scaled); 2 -> Vt permuted:
// within each 64-wide m tile, p = (m&32)|(((m>>2)&3)<<3)|(((m>>4)&1)<<2)|(m&3).
// ---------------------------------------------------------------------------
__global__ __launch_bounds__(256, 2) void proj_bf16(
    const bf16_t* __restrict__ Xb, const bf16_t* __restrict__ Wt,
    bf16_t* __restrict__ Qb, bf16_t* __restrict__ Kb, bf16_t* __restrict__ Vt)
{
    __shared__ bf16_t Ab[2][128 * 64];
    __shared__ bf16_t Bb[2][128 * 64];

    const int tid = threadIdx.x;
    const int w = tid >> 6, l = tid & 63, g = l >> 4, lr = l & 15;
    const int m0 = blockIdx.x * 128;
    const int mat = blockIdx.y >> 2;
    const int n0 = (blockIdx.y & 3) * 128;
    const bf16_t* Wm = Wt + (size_t)mat * 262144;
    const int wm = (w >> 1) * 64, wn = (w & 1) * 64;

#define STAGE_P(buf, k0v)                                                   \
    do {                                                                    \
        for (int t = 0; t < 4; ++t) {                                       \
            const int rb = w * 32 + t * 8;                                  \
            const int row = rb + (l >> 3);                                  \
            const int cb = ((l & 7) << 4) ^ ((row & 7) << 4);               \
            gload16(&Xb[(size_t)(m0 + row) * 512 + (k0v) + (cb >> 1)],      \
                    &Ab[buf][rb * 64]);                                     \
            gload16(&Wm[(size_t)(n0 + row) * 512 + (k0v) + (cb >> 1)],      \
                    &Bb[buf][rb * 64]);                                     \
        }                                                                   \
    } while (0)

    f32x4 acc[4][4];
    const f32x4 z4 = {0.f, 0.f, 0.f, 0.f};
#pragma unroll
    for (int i = 0; i < 4; ++i)
#pragma unroll
        for (int j = 0; j < 4; ++j) acc[i][j] = z4;

    STAGE_P(0, 0);
    __syncthreads();

    for (int kk = 0; kk < 8; ++kk) {
        const int cur = kk & 1;
        if (kk + 1 < 8) STAGE_P(cur ^ 1, (kk + 1) * 64);

        bf16x8 a[4][2], bq[4][2];
#pragma unroll
        for (int fa = 0; fa < 4; ++fa)
#pragma unroll
            for (int dh = 0; dh < 2; ++dh) {
                a[fa][dh]  = lds8(Ab[cur], wm + fa * 16 + lr, dh * 64 + g * 16);
                bq[fa][dh] = lds8(Bb[cur], wn + fa * 16 + lr, dh * 64 + g * 16);
            }
        __builtin_amdgcn_s_setprio(1);
#pragma unroll
        for (int fa = 0; fa < 4; ++fa)
#pragma unroll
            for (int fb = 0; fb < 4; ++fb) {
                acc[fa][fb] = MFMA16(a[fa][0], bq[fb][0], acc[fa][fb]);
                acc[fa][fb] = MFMA16(a[fa][1], bq[fb][1], acc[fa][fb]);
            }
        __builtin_amdgcn_s_setprio(0);
        __syncthreads();
    }
#undef STAGE_P

#pragma unroll
    for (int fa = 0; fa < 4; ++fa)
#pragma unroll
        for (int fb = 0; fb < 4; ++fb)
#pragma unroll
            for (int j = 0; j < 4; ++j) {
                const int m = m0 + wm + fa * 16 + g * 4 + j;
                const int n = n0 + wn + fb * 16 + lr;
                const bf16_t val = (bf16_t)acc[fa][fb][j];
                if (mat == 0) {
                    Qb[(size_t)m * 512 + n] = val;
                } else if (mat == 1) {
                    Kb[(size_t)m * 512 + n] = val;
                } else {
                    const int b_ = m >> 12, mm = m & 4095;
                    const int hh = n >> 6, d = n & 63;
                    const int loc = mm & 63;
                    const int mperm = (mm & ~63) | (loc & 32) |
                                      (((loc >> 2) & 3) << 3) |
                                      (((loc >> 4) & 1) << 2) | (loc & 3);
                    Vt[((size_t)((b_ * 8 + hh) * 64 + d)) * 4096 + mperm] = val;
                }
            }
}

// ---------------------------------------------------------------------------
// Legacy fp32-input projection (fallback for small ws).
// ---------------------------------------------------------------------------
__global__ __launch_bounds__(256) void proj_kernel(
    const float* __restrict__ X,
    const float* __restrict__ Wq, const float* __restrict__ Wk,
    const float* __restrict__ Wv,
    bf16_t* __restrict__ Qb, bf16_t* __restrict__ Kb, bf16_t* __restrict__ Vt)
{
    __shared__ bf16_t Ax[128][40];
    __shared__ bf16_t Wtl[64][40];

    const int mode = blockIdx.z;
    const float* W = (mode == 0) ? Wq : (mode == 1 ? Wk : Wv);
    bf16_t* C = (mode == 0) ? Qb : (mode == 1 ? Kb : Vt);

    const int tid = threadIdx.x;
    const int w = tid >> 6, l = tid & 63, g = l >> 4, lr = l & 15;
    const int m0 = blockIdx.x * 128, n0 = blockIdx.y * 64;

    f32x4 acc[2][4];
    const f32x4 z4 = {0.f, 0.f, 0.f, 0.f};
    for (int i = 0; i < 2; ++i)
        for (int j = 0; j < 4; ++j) acc[i][j] = z4;

    for (int k0 = 0; k0 < 512; k0 += 32) {
        {
            const int c4 = (tid & 7) * 4;
            for (int r = 0; r < 4; ++r) {
                const int row = (tid >> 3) + r * 32;
                const float4 v = *reinterpret_cast<const float4*>(
                    &X[(size_t)(m0 + row) * 512 + k0 + c4]);
                bf16x4 o;
                o[0] = (bf16_t)v.x; o[1] = (bf16_t)v.y;
                o[2] = (bf16_t)v.z; o[3] = (bf16_t)v.w;
                *reinterpret_cast<bf16x4*>(&Ax[row][c4]) = o;
            }
        }
        {
            const int c4 = (tid & 15) * 4;
            for (int r = 0; r < 2; ++r) {
                const int krow = (tid >> 4) + r * 16;
                const float4 v = *reinterpret_cast<const float4*>(
                    &W[(size_t)(k0 + krow) * 512 + n0 + c4]);
                Wtl[c4 + 0][krow] = (bf16_t)v.x;
                Wtl[c4 + 1][krow] = (bf16_t)v.y;
                Wtl[c4 + 2][krow] = (bf16_t)v.z;
                Wtl[c4 + 3][krow] = (bf16_t)v.w;
            }
        }
        __syncthreads();

        bf16x8 a[2], bq[4];
        for (int fr = 0; fr < 2; ++fr)
            a[fr] = *reinterpret_cast<const bf16x8*>(&Ax[w * 32 + fr * 16 + lr][g * 8]);
        for (int fn = 0; fn < 4; ++fn)
            bq[fn] = *reinterpret_cast<const bf16x8*>(&Wtl[fn * 16 + lr][g * 8]);
        for (int fr = 0; fr < 2; ++fr)
            for (int fn = 0; fn < 4; ++fn)
                acc[fr][fn] = MFMA16(a[fr], bq[fn], acc[fr][fn]);
        __syncthreads();
    }

    const float SCL = 0.125f * 1.44269504088896f;
    for (int fr = 0; fr < 2; ++fr)
        for (int fn = 0; fn < 4; ++fn)
            for (int j = 0; j < 4; ++j) {
                const int m = m0 + w * 32 + fr * 16 + g * 4 + j;
                const int n = n0 + fn * 16 + lr;
                float vf = acc[fr][fn][j];
                if (mode == 1) vf *= SCL;
                const bf16_t val = (bf16_t)vf;
                if (mode <= 1) {
                    C[(size_t)m * 512 + n] = val;
                } else {
                    const int b_ = m >> 12, mm = m & 4095;
                    const int hh = n >> 6, d = n & 63;
                    const int loc = mm & 63;
                    const int mperm = (mm & ~63) | (loc & 32) |
                                      (((loc >> 2) & 3) << 3) |
                                      (((loc >> 4) & 1) << 2) | (loc & 3);
                    C[((size_t)((b_ * 8 + hh) * 64 + d)) * 4096 + mperm] = val;
                }
            }
}

// ---------------------------------------------------------------------------
// Attention core: grid 256*nq blocks (XCD-swizzled), 4 fat waves x 64 n-rows
// = 256 n-rows per block, ONE shared m-stream (32 KB LDS, double-buffered)
// -> 4 blocks/CU, 16 waves/CU. m-axis split nq ways ACROSS blocks; partials
// are max-free sums: raw numerator fp16 + denominator fp32, combined later.
// Swapped QK^T keeps P in registers; denom via ones-MFMA.
// ---------------------------------------------------------------------------
__global__ __launch_bounds__(256, 4) void attn_kernel(
    const bf16_t* __restrict__ Kb, const bf16_t* __restrict__ Qb,
    const bf16_t* __restrict__ Vt, float* __restrict__ Out,
    _Float16* __restrict__ pO, float* __restrict__ pD, int nq)
{
    __shared__ __align__(16) char smem[32768];
    // Q tile:  smem + buf*8192          [64 m][128B d, swizzled]
    // V tile:  smem + 16384 + buf*8192  [64 d][128B m', swizzled]

    const int tid = threadIdx.x;
    const int w = tid >> 6, l = tid & 63, g = l >> 4, lr = l & 15;

    const int nblk = 256 * nq, cpx = nblk >> 3;
    const int id = (blockIdx.x & 7) * cpx + (blockIdx.x >> 3);  // XCD swizzle
    int bh, nb, q;
    if (nq == 4) { bh = id >> 6; nb = (id >> 2) & 15; q = id & 3; }
    else         { bh = id >> 4; nb = id & 15;        q = 0;     }
    const int b = bh >> 3, hd = bh & 7;
    const int n0 = nb * 256;          // block n-base (256 rows)
    const int ntiles = 64 / nq;
    const int t0 = q * ntiles;        // first m-tile

#define QL(buf) ((bf16_t*)(smem + (buf) * 8192))
#define VL(buf) ((bf16_t*)(smem + 16384 + (buf) * 8192))

    // K B-fragments in registers: wave w covers n-rows n0 + w*64 .. +63
    bf16x8 ak[4][2];
#pragma unroll
    for (int fr = 0; fr < 4; ++fr)
#pragma unroll
        for (int dh = 0; dh < 2; ++dh)
            ak[fr][dh] = *reinterpret_cast<const bf16x8*>(
                &Kb[(size_t)(b * 4096 + n0 + w * 64 + fr * 16 + lr) * 512 +
                    hd * 64 + dh * 32 + g * 8]);

    bf16x8 ones;
#pragma unroll
    for (int i = 0; i < 8; ++i) ones[i] = (bf16_t)1.0f;

    // 4 waves cooperatively stage the shared 64-row Q and V tiles
#define STAGE(buf, m0v)                                                              \
    do {                                                                             \
        for (int t = 0; t < 2; ++t) {                                                \
            const int rb = w * 16 + t * 8;                                           \
            const int row = rb + (l >> 3);                                           \
            const int cb = ((l & 7) << 4) ^ ((row & 7) << 4);                        \
            gload16(&Qb[(size_t)(b * 4096 + (m0v) + row) * 512 + hd * 64 + (cb >> 1)],\
                    QL(buf) + rb * 64);                                              \
            gload16(&Vt[((size_t)(bh * 64 + row)) * 4096 + (m0v) + (cb >> 1)],       \
                    VL(buf) + rb * 64);                                              \
        }                                                                            \
    } while (0)

    f32x4 acc[4][4];
    f32x4 dacc[4];
    const f32x4 z4 = {0.f, 0.f, 0.f, 0.f};
#pragma unroll
    for (int fr = 0; fr < 4; ++fr) {
        dacc[fr] = z4;
#pragma unroll
        for (int j = 0; j < 4; ++j) acc[fr][j] = z4;
    }

    auto compute_tile = [&](int cur) {
        const bf16_t* qb = QL(cur);
        const bf16_t* vb = VL(cur);
        bf16x8 pa[4][2];
#pragma unroll
        for (int c = 0; c < 2; ++c) {
            f32x4 s[2][4];
#pragma unroll
            for (int mm = 0; mm < 2; ++mm)
#pragma unroll
                for (int fr = 0; fr < 4; ++fr) s[mm][fr] = z4;
            __builtin_amdgcn_s_setprio(1);
#pragma unroll
            for (int mm = 0; mm < 2; ++mm) {
                const int r = (c * 2 + mm) * 16 + lr;
                const bf16x8 a0 = lds8(qb, r, g * 16);
                const bf16x8 a1 = lds8(qb, r, 64 + g * 16);
#pragma unroll
                for (int fr = 0; fr < 4; ++fr) {
                    s[mm][fr] = MFMA16(a0, ak[fr][0], s[mm][fr]);
                    s[mm][fr] = MFMA16(a1, ak[fr][1], s[mm][fr]);
                }
            }
            __builtin_amdgcn_s_setprio(0);
#pragma unroll
            for (int fr = 0; fr < 4; ++fr)
#pragma unroll
                for (int e = 0; e < 8; ++e)
                    pa[fr][c][e] = (bf16_t)__builtin_amdgcn_exp2f(
                        s[e >> 2][fr][e & 3]);
        }
        __builtin_amdgcn_s_setprio(1);
#pragma unroll
        for (int fr = 0; fr < 4; ++fr) {
            dacc[fr] = MFMA16(pa[fr][0], ones, dacc[fr]);
            dacc[fr] = MFMA16(pa[fr][1], ones, dacc[fr]);
        }
#pragma unroll
        for (int fd = 0; fd < 4; ++fd) {
            const bf16x8 vb0 = lds8(vb, fd * 16 + lr, g * 16);
            const bf16x8 vb1 = lds8(vb, fd * 16 + lr, 64 + g * 16);
#pragma unroll
            for (int fr = 0; fr < 4; ++fr) {
                acc[fr][fd] = MFMA16(pa[fr][0], vb0, acc[fr][fd]);
                acc[fr][fd] = MFMA16(pa[fr][1], vb1, acc[fr][fd]);
            }
        }
        __builtin_amdgcn_s_setprio(0);
    };

    STAGE(0, t0 * 64);
    __syncthreads();

    for (int it = 0; it < ntiles - 1; ++it) {
        STAGE((it + 1) & 1, (t0 + it + 1) * 64);
        compute_tile(it & 1);
        __syncthreads();
    }
    compute_tile((ntiles - 1) & 1);

    if (nq == 1) {
        float linv[4][4];
#pragma unroll
        for (int fr = 0; fr < 4; ++fr)
#pragma unroll
            for (int j = 0; j < 4; ++j) linv[fr][j] = 1.0f / dacc[fr][j];
#pragma unroll
        for (int fr = 0; fr < 4; ++fr)
#pragma unroll
            for (int fd = 0; fd < 4; ++fd)
#pragma unroll
                for (int j = 0; j < 4; ++j) {
                    const int n = n0 + w * 64 + fr * 16 + g * 4 + j;
                    Out[((size_t)(b * 4096 + n)) * 512 + hd * 64 + fd * 16 + lr] =
                        acc[fr][fd][j] * linv[fr][j];
                }
    } else {
        const size_t qb_ = ((size_t)(q * 16 + bh)) << 18;
#pragma unroll
        for (int fr = 0; fr < 4; ++fr)
#pragma unroll
            for (int fd = 0; fd < 4; ++fd)
#pragma unroll
                for (int j = 0; j < 4; ++j) {
                    const int n = n0 + w * 64 + fr * 16 + g * 4 + j;
                    pO[qb_ + ((size_t)n << 6) + fd * 16 + lr] = (_Float16)acc[fr][fd][j];
                }
        if (lr == 0) {
#pragma unroll
            for (int fr = 0; fr < 4; ++fr)
#pragma unroll
                for (int j = 0; j < 4; ++j) {
                    const int n = n0 + w * 64 + fr * 16 + g * 4 + j;
                    pD[(((size_t)(q * 16 + bh)) << 12) + n] = dacc[fr][j];
                }
        }
    }
#undef STAGE
#undef QL
#undef VL
}

// ---------------------------------------------------------------------------
// Combine the 4 m-quarter partials: out = (sum_q num_q) / (sum_q den_q).
// ---------------------------------------------------------------------------
__global__ __launch_bounds__(256) void combine_kernel(
    const _Float16* __restrict__ pO, const float* __restrict__ pD,
    float* __restrict__ Out)
{
    const size_t i2 = ((size_t)blockIdx.x * 256 + threadIdx.x) * 2;
    const int d = (int)(i2 & 63);
    const int n = (int)((i2 >> 6) & 4095);
    const int bh = (int)(i2 >> 18);

    float s0 = 0.f, s1 = 0.f, den = 0.f;
#pragma unroll
    for (int q = 0; q < 4; ++q) {
        const f16x2 v = *reinterpret_cast<const f16x2*>(
            &pO[(((size_t)(q * 16 + bh)) << 18) + ((size_t)n << 6) + d]);
        s0 += (float)v[0];
        s1 += (float)v[1];
        den += pD[(((size_t)(q * 16 + bh)) << 12) + n];
    }
    const float inv = 1.0f / den;
    float2 o; o.x = s0 * inv; o.y = s1 * inv;
    *reinterpret_cast<float2*>(
        &Out[((size_t)((bh >> 3) * 4096 + n)) * 512 + (bh & 7) * 64 + d]) = o;
}

extern "C" void kernel_launch(void* const* d_in, const int* in_sizes, int n_in,
                              void* d_out, int out_size, void* d_ws, size_t ws_size,
                              hipStream_t stream)
{
    const float* x  = (const float*)d_in[0];
    const float* Wk = (const float*)d_in[1];
    const float* Wq = (const float*)d_in[2];
    const float* Wv = (const float*)d_in[3];
    float* out = (float*)d_out;

    char* ws = (char*)d_ws;
    bf16_t* Kb = (bf16_t*)ws;                    // [0, 8 MB)
    bf16_t* Qb = Kb + (size_t)4194304;           // [8, 16 MB)
    bf16_t* Vt = Qb + (size_t)4194304;           // [16, 24 MB)
    bf16_t* Xb = (bf16_t*)(ws + 25165824);       // [24, 32 MB)   (dead after proj)
    bf16_t* Wt = Xb + (size_t)4194304;           // [32, 33.5 MB) (dead after proj)
    _Float16* pO = (_Float16*)(ws + 25165824);   // [24, 56 MB)   overlays Xb/Wt
    float*    pD = (float*)(ws + 58720256);      // [56, 57 MB)

    const size_t NEED_PRE   = 35127296;   // through Wt
    const size_t NEED_SPLIT = 59768832;   // through pD
    const bool has_pre   = ws_size >= NEED_PRE;
    const bool has_split = ws_size >= NEED_SPLIT;

    if (has_pre) {
        hipLaunchKernelGGL(convert_x, dim3(2048), dim3(256), 0, stream, x, Xb);
        hipLaunchKernelGGL(transpose_w, dim3(8, 8, 3), dim3(256), 0, stream,
                           Wq, Wk, Wv, Wt);
        hipLaunchKernelGGL(proj_bf16, dim3(64, 12), dim3(256), 0, stream,
                           Xb, Wt, Qb, Kb, Vt);
    } else {
        hipLaunchKernelGGL(proj_kernel, dim3(64, 8, 3), dim3(256), 0, stream,
                           x, Wq, Wk, Wv, Qb, Kb, Vt);
    }

    if (has_split) {
        hipLaunchKernelGGL(attn_kernel, dim3(1024), dim3(256), 0, stream,
                           Kb, Qb, Vt, out, pO, pD, 4);
        hipLaunchKernelGGL(combine_kernel, dim3(8192), dim3(256), 0, stream,
                           pO, pD, out);
    } else {
        hipLaunchKernelGGL(attn_kernel, dim3(256), dim3(256), 0, stream,
                           Kb, Qb, Vt, out, pO, pD, 1);
    }
}

// Round 8
// 163.936 us; speedup vs baseline: 2.1783x; 2.1783x over previous
//
#include <hip/hip_runtime.h>
#include <hip/hip_bf16.h>

typedef __bf16 bf16_t;
typedef bf16_t bf16x8 __attribute__((ext_vector_type(8)));
typedef bf16_t bf16x4 __attribute__((ext_vector_type(4)));
typedef float f32x4 __attribute__((ext_vector_type(4)));

#define MFMA16(a, b, c) __builtin_amdgcn_mfma_f32_16x16x32_bf16(a, b, c, 0, 0, 0)

typedef __attribute__((address_space(3))) unsigned int lds_u32_t;
typedef __attribute__((address_space(1))) const unsigned int glb_u32_t;

__device__ __forceinline__ void gload16(const void* g, void* l) {
    __builtin_amdgcn_global_load_lds((glb_u32_t*)g, (lds_u32_t*)l, 16, 0, 0);
}

// swizzled LDS read: row stride 128B, byte-col ^= (row&7)<<4
__device__ __forceinline__ bf16x8 lds8(const bf16_t* base, int row, int cb) {
    return *reinterpret_cast<const bf16x8*>(
        reinterpret_cast<const char*>(base) + row * 128 + (cb ^ ((row & 7) << 4)));
}

// ---------------------------------------------------------------------------
// Pre-pass 1: X fp32 -> bf16
// ---------------------------------------------------------------------------
__global__ __launch_bounds__(256) void convert_x(
    const float* __restrict__ X, bf16_t* __restrict__ Xb)
{
    const size_t i = ((size_t)blockIdx.x * 256 + threadIdx.x) * 8;
    const float4 v0 = *reinterpret_cast<const float4*>(&X[i]);
    const float4 v1 = *reinterpret_cast<const float4*>(&X[i + 4]);
    bf16x8 o;
    o[0] = (bf16_t)v0.x; o[1] = (bf16_t)v0.y; o[2] = (bf16_t)v0.z; o[3] = (bf16_t)v0.w;
    o[4] = (bf16_t)v1.x; o[5] = (bf16_t)v1.y; o[6] = (bf16_t)v1.z; o[7] = (bf16_t)v1.w;
    *reinterpret_cast<bf16x8*>(&Xb[i]) = o;
}

// ---------------------------------------------------------------------------
// Pre-pass 2: W [k][n] fp32 -> Wt [mat][n][k] bf16; K-matrix scaled log2(e)/8.
// ---------------------------------------------------------------------------
__global__ __launch_bounds__(256) void transpose_w(
    const float* __restrict__ Wq, const float* __restrict__ Wk,
    const float* __restrict__ Wv, bf16_t* __restrict__ Wt)
{
    __shared__ float T[64][65];
    const int mat = blockIdx.z;
    const float* W = (mat == 0) ? Wq : (mat == 1 ? Wk : Wv);
    const int k0 = blockIdx.x * 64, n0 = blockIdx.y * 64;
    const int r = threadIdx.x >> 4, c4 = (threadIdx.x & 15) * 4;

    for (int rep = 0; rep < 4; ++rep) {
        const int row = r + rep * 16;
        const float4 v = *reinterpret_cast<const float4*>(&W[(size_t)(k0 + row) * 512 + n0 + c4]);
        T[row][c4 + 0] = v.x; T[row][c4 + 1] = v.y;
        T[row][c4 + 2] = v.z; T[row][c4 + 3] = v.w;
    }
    __syncthreads();
    const float scl = (mat == 1) ? 0.1803368801111204f : 1.0f;  // log2(e)/8
    for (int rep = 0; rep < 4; ++rep) {
        const int nrow = r + rep * 16;
        bf16x4 o;
        for (int e = 0; e < 4; ++e) o[e] = (bf16_t)(T[c4 + e][nrow] * scl);
        *reinterpret_cast<bf16x4*>(&Wt[(size_t)mat * 262144 + (size_t)(n0 + nrow) * 512 + k0 + c4]) = o;
    }
}

// ---------------------------------------------------------------------------
// bf16 projection GEMM, 128x128 tile, BK=64, 4 waves (each 64x64 out).
// grid (64, 12): mat = y>>2, n0 = (y&3)*128.
// mat 0 -> Qb row-major; 1 -> Kb row-major (K pre-scaled); 2 -> Vt permuted:
// within each 64-wide m tile, p = (m&32)|(((m>>2)&3)<<3)|(((m>>4)&1)<<2)|(m&3).
// ---------------------------------------------------------------------------
__global__ __launch_bounds__(256, 2) void proj_bf16(
    const bf16_t* __restrict__ Xb, const bf16_t* __restrict__ Wt,
    bf16_t* __restrict__ Qb, bf16_t* __restrict__ Kb, bf16_t* __restrict__ Vt)
{
    __shared__ bf16_t Ab[2][128 * 64];
    __shared__ bf16_t Bb[2][128 * 64];

    const int tid = threadIdx.x;
    const int w = tid >> 6, l = tid & 63, g = l >> 4, lr = l & 15;
    const int m0 = blockIdx.x * 128;
    const int mat = blockIdx.y >> 2;
    const int n0 = (blockIdx.y & 3) * 128;
    const bf16_t* Wm = Wt + (size_t)mat * 262144;
    const int wm = (w >> 1) * 64, wn = (w & 1) * 64;

#define STAGE_P(buf, k0v)                                                   \
    do {                                                                    \
        for (int t = 0; t < 4; ++t) {                                       \
            const int rb = w * 32 + t * 8;                                  \
            const int row = rb + (l >> 3);                                  \
            const int cb = ((l & 7) << 4) ^ ((row & 7) << 4);               \
            gload16(&Xb[(size_t)(m0 + row) * 512 + (k0v) + (cb >> 1)],      \
                    &Ab[buf][rb * 64]);                                     \
            gload16(&Wm[(size_t)(n0 + row) * 512 + (k0v) + (cb >> 1)],      \
                    &Bb[buf][rb * 64]);                                     \
        }                                                                   \
    } while (0)

    f32x4 acc[4][4];
    const f32x4 z4 = {0.f, 0.f, 0.f, 0.f};
#pragma unroll
    for (int i = 0; i < 4; ++i)
#pragma unroll
        for (int j = 0; j < 4; ++j) acc[i][j] = z4;

    STAGE_P(0, 0);
    __syncthreads();

    for (int kk = 0; kk < 8; ++kk) {
        const int cur = kk & 1;
        if (kk + 1 < 8) STAGE_P(cur ^ 1, (kk + 1) * 64);

        bf16x8 a[4][2], bq[4][2];
#pragma unroll
        for (int fa = 0; fa < 4; ++fa)
#pragma unroll
            for (int dh = 0; dh < 2; ++dh) {
                a[fa][dh]  = lds8(Ab[cur], wm + fa * 16 + lr, dh * 64 + g * 16);
                bq[fa][dh] = lds8(Bb[cur], wn + fa * 16 + lr, dh * 64 + g * 16);
            }
        __builtin_amdgcn_s_setprio(1);
#pragma unroll
        for (int fa = 0; fa < 4; ++fa)
#pragma unroll
            for (int fb = 0; fb < 4; ++fb) {
                acc[fa][fb] = MFMA16(a[fa][0], bq[fb][0], acc[fa][fb]);
                acc[fa][fb] = MFMA16(a[fa][1], bq[fb][1], acc[fa][fb]);
            }
        __builtin_amdgcn_s_setprio(0);
        __syncthreads();
    }
#undef STAGE_P

#pragma unroll
    for (int fa = 0; fa < 4; ++fa)
#pragma unroll
        for (int fb = 0; fb < 4; ++fb)
#pragma unroll
            for (int j = 0; j < 4; ++j) {
                const int m = m0 + wm + fa * 16 + g * 4 + j;
                const int n = n0 + wn + fb * 16 + lr;
                const bf16_t val = (bf16_t)acc[fa][fb][j];
                if (mat == 0) {
                    Qb[(size_t)m * 512 + n] = val;
                } else if (mat == 1) {
                    Kb[(size_t)m * 512 + n] = val;
                } else {
                    const int b_ = m >> 12, mm = m & 4095;
                    const int hh = n >> 6, d = n & 63;
                    const int loc = mm & 63;
                    const int mperm = (mm & ~63) | (loc & 32) |
                                      (((loc >> 2) & 3) << 3) |
                                      (((loc >> 4) & 1) << 2) | (loc & 3);
                    Vt[((size_t)((b_ * 8 + hh) * 64 + d)) * 4096 + mperm] = val;
                }
            }
}

// ---------------------------------------------------------------------------
// Legacy fp32-input projection (fallback for small ws).
// ---------------------------------------------------------------------------
__global__ __launch_bounds__(256) void proj_kernel(
    const float* __restrict__ X,
    const float* __restrict__ Wq, const float* __restrict__ Wk,
    const float* __restrict__ Wv,
    bf16_t* __restrict__ Qb, bf16_t* __restrict__ Kb, bf16_t* __restrict__ Vt)
{
    __shared__ bf16_t Ax[128][40];
    __shared__ bf16_t Wtl[64][40];

    const int mode = blockIdx.z;
    const float* W = (mode == 0) ? Wq : (mode == 1 ? Wk : Wv);
    bf16_t* C = (mode == 0) ? Qb : (mode == 1 ? Kb : Vt);

    const int tid = threadIdx.x;
    const int w = tid >> 6, l = tid & 63, g = l >> 4, lr = l & 15;
    const int m0 = blockIdx.x * 128, n0 = blockIdx.y * 64;

    f32x4 acc[2][4];
    const f32x4 z4 = {0.f, 0.f, 0.f, 0.f};
    for (int i = 0; i < 2; ++i)
        for (int j = 0; j < 4; ++j) acc[i][j] = z4;

    for (int k0 = 0; k0 < 512; k0 += 32) {
        {
            const int c4 = (tid & 7) * 4;
            for (int r = 0; r < 4; ++r) {
                const int row = (tid >> 3) + r * 32;
                const float4 v = *reinterpret_cast<const float4*>(
                    &X[(size_t)(m0 + row) * 512 + k0 + c4]);
                bf16x4 o;
                o[0] = (bf16_t)v.x; o[1] = (bf16_t)v.y;
                o[2] = (bf16_t)v.z; o[3] = (bf16_t)v.w;
                *reinterpret_cast<bf16x4*>(&Ax[row][c4]) = o;
            }
        }
        {
            const int c4 = (tid & 15) * 4;
            for (int r = 0; r < 2; ++r) {
                const int krow = (tid >> 4) + r * 16;
                const float4 v = *reinterpret_cast<const float4*>(
                    &W[(size_t)(k0 + krow) * 512 + n0 + c4]);
                Wtl[c4 + 0][krow] = (bf16_t)v.x;
                Wtl[c4 + 1][krow] = (bf16_t)v.y;
                Wtl[c4 + 2][krow] = (bf16_t)v.z;
                Wtl[c4 + 3][krow] = (bf16_t)v.w;
            }
        }
        __syncthreads();

        bf16x8 a[2], bq[4];
        for (int fr = 0; fr < 2; ++fr)
            a[fr] = *reinterpret_cast<const bf16x8*>(&Ax[w * 32 + fr * 16 + lr][g * 8]);
        for (int fn = 0; fn < 4; ++fn)
            bq[fn] = *reinterpret_cast<const bf16x8*>(&Wtl[fn * 16 + lr][g * 8]);
        for (int fr = 0; fr < 2; ++fr)
            for (int fn = 0; fn < 4; ++fn)
                acc[fr][fn] = MFMA16(a[fr], bq[fn], acc[fr][fn]);
        __syncthreads();
    }

    const float SCL = 0.125f * 1.44269504088896f;
    for (int fr = 0; fr < 2; ++fr)
        for (int fn = 0; fn < 4; ++fn)
            for (int j = 0; j < 4; ++j) {
                const int m = m0 + w * 32 + fr * 16 + g * 4 + j;
                const int n = n0 + fn * 16 + lr;
                float vf = acc[fr][fn][j];
                if (mode == 1) vf *= SCL;
                const bf16_t val = (bf16_t)vf;
                if (mode <= 1) {
                    C[(size_t)m * 512 + n] = val;
                } else {
                    const int b_ = m >> 12, mm = m & 4095;
                    const int hh = n >> 6, d = n & 63;
                    const int loc = mm & 63;
                    const int mperm = (mm & ~63) | (loc & 32) |
                                      (((loc >> 2) & 3) << 3) |
                                      (((loc >> 4) & 1) << 2) | (loc & 3);
                    C[((size_t)((b_ * 8 + hh) * 64 + d)) * 4096 + mperm] = val;
                }
            }
}

// ---------------------------------------------------------------------------
// Attention core: grid 256*nq (XCD-swizzled, q SLOWEST: id = q*256+bh*16+nb),
// 4 fat waves x 64 n-rows = 256 rows/block, ONE m-stream, 3-buffer LDS
// (48 KB -> 3 blocks/CU), counted-vmcnt single-barrier pipeline (T3/T4):
// per tile { vmcnt(4); s_barrier; STAGE(t+2); compute(t) }.
// Swapped QK^T keeps P in registers; no-max softmax; denom via ones-MFMA.
// nq>1: partial numerator bf16 full-line packed (pO[n][lr*4+fd]) + pD fp32.
// ---------------------------------------------------------------------------
__global__ __launch_bounds__(256, 3) void attn_kernel(
    const bf16_t* __restrict__ Kb, const bf16_t* __restrict__ Qb,
    const bf16_t* __restrict__ Vt, float* __restrict__ Out,
    bf16_t* __restrict__ pO, float* __restrict__ pD, int nq)
{
    __shared__ __align__(16) char smem[49152];
    // buffer b: Q tile at smem + b*16384 (8 KB), V tile at +8192 (8 KB)

    const int tid = threadIdx.x;
    const int w = tid >> 6, l = tid & 63, g = l >> 4, lr = l & 15;

    const int cpx = (256 * nq) >> 3;
    const int id = ((int)blockIdx.x & 7) * cpx + ((int)blockIdx.x >> 3);
    const int q = id >> 8;                 // m-quarter (slowest)
    const int bh = (id >> 4) & 15;
    const int nb = id & 15;
    const int b = bh >> 3, hd = bh & 7;
    const int n0 = nb * 256;
    const int ntiles = 64 / nq;
    const int t0 = q * ntiles;

    // K B-fragments in registers: wave w covers n-rows n0 + w*64 .. +63
    bf16x8 ak[4][2];
#pragma unroll
    for (int fr = 0; fr < 4; ++fr)
#pragma unroll
        for (int dh = 0; dh < 2; ++dh)
            ak[fr][dh] = *reinterpret_cast<const bf16x8*>(
                &Kb[(size_t)(b * 4096 + n0 + w * 64 + fr * 16 + lr) * 512 +
                    hd * 64 + dh * 32 + g * 8]);

    bf16x8 ones;
#pragma unroll
    for (int i = 0; i < 8; ++i) ones[i] = (bf16_t)1.0f;

    // 4 waves cooperatively stage the shared 64-row Q and V tiles
    // (4 gload16 per wave per STAGE -> vmcnt granularity = 4)
#define STAGE(buf, m0v)                                                              \
    do {                                                                             \
        char* qls = smem + (buf) * 16384;                                            \
        char* vls = qls + 8192;                                                      \
        for (int t = 0; t < 2; ++t) {                                                \
            const int rb = w * 16 + t * 8;                                           \
            const int row = rb + (l >> 3);                                           \
            const int cb = ((l & 7) << 4) ^ ((row & 7) << 4);                        \
            gload16(&Qb[(size_t)(b * 4096 + (m0v) + row) * 512 + hd * 64 + (cb >> 1)],\
                    qls + rb * 128);                                                 \
            gload16(&Vt[((size_t)(bh * 64 + row)) * 4096 + (m0v) + (cb >> 1)],       \
                    vls + rb * 128);                                                 \
        }                                                                            \
    } while (0)

    f32x4 acc[4][4];
    f32x4 dacc[4];
    const f32x4 z4 = {0.f, 0.f, 0.f, 0.f};
#pragma unroll
    for (int fr = 0; fr < 4; ++fr) {
        dacc[fr] = z4;
#pragma unroll
        for (int j = 0; j < 4; ++j) acc[fr][j] = z4;
    }

    auto compute_tile = [&](int buf) {
        const bf16_t* qb = (const bf16_t*)(smem + buf * 16384);
        const bf16_t* vb = (const bf16_t*)(smem + buf * 16384 + 8192);
        bf16x8 pa[4][2];
#pragma unroll
        for (int c = 0; c < 2; ++c) {
            f32x4 s[2][4];
#pragma unroll
            for (int mm = 0; mm < 2; ++mm)
#pragma unroll
                for (int fr = 0; fr < 4; ++fr) s[mm][fr] = z4;
            __builtin_amdgcn_s_setprio(1);
#pragma unroll
            for (int mm = 0; mm < 2; ++mm) {
                const int r = (c * 2 + mm) * 16 + lr;
                const bf16x8 a0 = lds8(qb, r, g * 16);
                const bf16x8 a1 = lds8(qb, r, 64 + g * 16);
#pragma unroll
                for (int fr = 0; fr < 4; ++fr) {
                    s[mm][fr] = MFMA16(a0, ak[fr][0], s[mm][fr]);
                    s[mm][fr] = MFMA16(a1, ak[fr][1], s[mm][fr]);
                }
            }
            __builtin_amdgcn_s_setprio(0);
#pragma unroll
            for (int fr = 0; fr < 4; ++fr)
#pragma unroll
                for (int e = 0; e < 8; ++e)
                    pa[fr][c][e] = (bf16_t)__builtin_amdgcn_exp2f(
                        s[e >> 2][fr][e & 3]);
        }
        __builtin_amdgcn_s_setprio(1);
#pragma unroll
        for (int fr = 0; fr < 4; ++fr) {
            dacc[fr] = MFMA16(pa[fr][0], ones, dacc[fr]);
            dacc[fr] = MFMA16(pa[fr][1], ones, dacc[fr]);
        }
#pragma unroll
        for (int fd = 0; fd < 4; ++fd) {
            const bf16x8 vb0 = lds8(vb, fd * 16 + lr, g * 16);
            const bf16x8 vb1 = lds8(vb, fd * 16 + lr, 64 + g * 16);
#pragma unroll
            for (int fr = 0; fr < 4; ++fr) {
                acc[fr][fd] = MFMA16(pa[fr][0], vb0, acc[fr][fd]);
                acc[fr][fd] = MFMA16(pa[fr][1], vb1, acc[fr][fd]);
            }
        }
        __builtin_amdgcn_s_setprio(0);
    };

    // ---- 3-buffer counted-vmcnt pipeline, one s_barrier per tile ----
    STAGE(0, t0 * 64);
    STAGE(1, (t0 + 1) * 64);

    int cb_ = 0, sb_ = 2;
    for (int it = 0; it < ntiles - 1; ++it) {
        asm volatile("s_waitcnt vmcnt(4)" ::: "memory");
        __builtin_amdgcn_s_barrier();
        if (it + 2 < ntiles) STAGE(sb_, (t0 + it + 2) * 64);
        compute_tile(cb_);
        cb_ = (cb_ == 2) ? 0 : cb_ + 1;
        sb_ = (sb_ == 2) ? 0 : sb_ + 1;
    }
    asm volatile("s_waitcnt vmcnt(0)" ::: "memory");
    __builtin_amdgcn_s_barrier();
    compute_tile(cb_);

    if (nq == 1) {
        float linv[4][4];
#pragma unroll
        for (int fr = 0; fr < 4; ++fr)
#pragma unroll
            for (int j = 0; j < 4; ++j) linv[fr][j] = 1.0f / dacc[fr][j];
#pragma unroll
        for (int fr = 0; fr < 4; ++fr)
#pragma unroll
            for (int fd = 0; fd < 4; ++fd)
#pragma unroll
                for (int j = 0; j < 4; ++j) {
                    const int n = n0 + w * 64 + fr * 16 + g * 4 + j;
                    Out[((size_t)(b * 4096 + n)) * 512 + hd * 64 + fd * 16 + lr] =
                        acc[fr][fd][j] * linv[fr][j];
                }
    } else {
        // packed full-line partials: pO[(qb+n)*64 + lr*4 + fd] (bf16)
        const size_t rowb = ((size_t)(q * 16 + bh)) * 4096;
#pragma unroll
        for (int fr = 0; fr < 4; ++fr)
#pragma unroll
            for (int j = 0; j < 4; ++j) {
                const int n = n0 + w * 64 + fr * 16 + g * 4 + j;
                bf16x4 pk;
#pragma unroll
                for (int fd = 0; fd < 4; ++fd) pk[fd] = (bf16_t)acc[fr][fd][j];
                *reinterpret_cast<bf16x4*>(&pO[(rowb + n) * 64 + lr * 4]) = pk;
            }
        if (lr == 0) {
#pragma unroll
            for (int fr = 0; fr < 4; ++fr)
#pragma unroll
                for (int j = 0; j < 4; ++j) {
                    const int n = n0 + w * 64 + fr * 16 + g * 4 + j;
                    pD[rowb + n] = dacc[fr][j];
                }
        }
    }
#undef STAGE
}

// ---------------------------------------------------------------------------
// Combine 4 m-quarter partials. Thread T = (bh*4096 + n)*16 + lr handles
// d = lr + {0,16,32,48}: out = (sum_q num)/(sum_q den).
// ---------------------------------------------------------------------------
__global__ __launch_bounds__(256) void combine_kernel(
    const bf16_t* __restrict__ pO, const float* __restrict__ pD,
    float* __restrict__ Out)
{
    const int T = (int)blockIdx.x * 256 + threadIdx.x;
    const int lr = T & 15;
    const int n = (T >> 4) & 4095;
    const int bh = T >> 16;

    float s[4] = {0.f, 0.f, 0.f, 0.f};
    float den = 0.f;
#pragma unroll
    for (int q = 0; q < 4; ++q) {
        const size_t rowb = ((size_t)(q * 16 + bh)) * 4096 + n;
        const bf16x4 v = *reinterpret_cast<const bf16x4*>(&pO[rowb * 64 + lr * 4]);
#pragma unroll
        for (int fd = 0; fd < 4; ++fd) s[fd] += (float)v[fd];
        den += pD[rowb];
    }
    const float inv = 1.0f / den;
    const size_t base = ((size_t)((bh >> 3) * 4096 + n)) * 512 + (bh & 7) * 64;
#pragma unroll
    for (int fd = 0; fd < 4; ++fd) Out[base + fd * 16 + lr] = s[fd] * inv;
}

extern "C" void kernel_launch(void* const* d_in, const int* in_sizes, int n_in,
                              void* d_out, int out_size, void* d_ws, size_t ws_size,
                              hipStream_t stream)
{
    const float* x  = (const float*)d_in[0];
    const float* Wk = (const float*)d_in[1];
    const float* Wq = (const float*)d_in[2];
    const float* Wv = (const float*)d_in[3];
    float* out = (float*)d_out;

    char* ws = (char*)d_ws;
    bf16_t* Kb = (bf16_t*)ws;                    // [0, 8 MB)
    bf16_t* Qb = Kb + (size_t)4194304;           // [8, 16 MB)
    bf16_t* Vt = Qb + (size_t)4194304;           // [16, 24 MB)
    bf16_t* Xb = (bf16_t*)(ws + 25165824);       // [24, 32 MB)   (dead after proj)
    bf16_t* Wt = Xb + (size_t)4194304;           // [32, 33.5 MB) (dead after proj)
    bf16_t* pO = (bf16_t*)(ws + 25165824);       // [24, 56 MB)   overlays Xb/Wt
    float*  pD = (float*)(ws + 58720256);        // [56, 57 MB)

    const size_t NEED_PRE   = 35127296;   // through Wt
    const size_t NEED_SPLIT = 59768832;   // through pD
    const bool has_pre   = ws_size >= NEED_PRE;
    const bool has_split = ws_size >= NEED_SPLIT;

    if (has_pre) {
        hipLaunchKernelGGL(convert_x, dim3(2048), dim3(256), 0, stream, x, Xb);
        hipLaunchKernelGGL(transpose_w, dim3(8, 8, 3), dim3(256), 0, stream,
                           Wq, Wk, Wv, Wt);
        hipLaunchKernelGGL(proj_bf16, dim3(64, 12), dim3(256), 0, stream,
                           Xb, Wt, Qb, Kb, Vt);
    } else {
        hipLaunchKernelGGL(proj_kernel, dim3(64, 8, 3), dim3(256), 0, stream,
                           x, Wq, Wk, Wv, Qb, Kb, Vt);
    }

    if (has_split) {
        hipLaunchKernelGGL(attn_kernel, dim3(1024), dim3(256), 0, stream,
                           Kb, Qb, Vt, out, pO, pD, 4);
        hipLaunchKernelGGL(combine_kernel, dim3(4096), dim3(256), 0, stream,
                           pO, pD, out);
    } else {
        hipLaunchKernelGGL(attn_kernel, dim3(256), dim3(256), 0, stream,
                           Kb, Qb, Vt, out, pO, pD, 1);
    }
}